// Round 13
// baseline (76.225 us; speedup 1.0000x reference)
//
#include <hip/hip_runtime.h>
#include <math.h>

#define L      2048
#define DDIM   512
#define NBATCH 8
#define BM     256
#define BN     256
#define BK     64
#define NKT    (DDIM / BK)               // 8 K-tiles
#define NTJ    (L / BM)                  // 8
#define TOTAL_BLOCKS (NBATCH * NTJ * NTJ) // 512 (full matrix, no symmetry)

#define ALPHA  0.1f
#define BETA   0.3f
#define MARGIN 2.0f

typedef _Float16 f16x8 __attribute__((ext_vector_type(8)));
typedef __attribute__((ext_vector_type(4))) float f32x4;

// LDS: ring-2 of [A 256x64 f16 | B 256x64 f16] = 2 x 64KB = 128KB dynamic.
// Rows are 128B = 8 chunks of 16B; physical chunk = logical ^ (row&7)
// (proven conflict-free for 16-lane b128 quarters: R8/R12 + bank math).
#define TILE_SH 16384      // f16 per tile (32 KB)
#define BUFSZ   32768      // f16 per buffer (64 KB)
#define LDS_BYTES (2 * BUFSZ * 2)   // 131072

#define GLOAD_LDS16(g, l) __builtin_amdgcn_global_load_lds(              \
    (const __attribute__((address_space(1))) unsigned int*)(g),          \
    (__attribute__((address_space(3))) unsigned int*)(l), 16, 0, 0)

// ---------------------------------------------------------------------------
// Kernel 1: fp32 -> fp16 + per-row squared norms (exact fp32).
// ---------------------------------------------------------------------------
__global__ __launch_bounds__(256) void conv_kernel(const float* __restrict__ pred,
                                                   _Float16* __restrict__ h,
                                                   float* __restrict__ sq) {
    int w    = threadIdx.x >> 6;
    int lane = threadIdx.x & 63;
    int row  = blockIdx.x * 4 + w;
    const float* p = pred + (size_t)row * DDIM + lane * 8;
    float4 v0 = *(const float4*)(p);
    float4 v1 = *(const float4*)(p + 4);
    float vals[8] = {v0.x, v0.y, v0.z, v0.w, v1.x, v1.y, v1.z, v1.w};
    f16x8 hv;
    float s = 0.0f;
    #pragma unroll
    for (int i = 0; i < 8; ++i) {
        float x = vals[i];
        s = fmaf(x, x, s);
        hv[i] = (_Float16)x;
    }
    *(f16x8*)(h + (size_t)row * DDIM + lane * 8) = hv;
    #pragma unroll
    for (int off = 32; off > 0; off >>= 1) s += __shfl_down(s, off);
    if (lane == 0) sq[row] = s;
}

// ---------------------------------------------------------------------------
// Kernel 2: fp16 Gram GEMM, 256x256 tile, 8 waves (2Mx4N, per-wave 128x64 =
// 8x4 frags of 16x16x32), BK=64, ring-2 LDS, 4 phases/K-tile:
//  ph0: vmcnt(0); bar; read aQ(mh0)+b(nf01); STAGE(j+1 -> other buf);
//       lgkm0; prio1; 16 MFMA Q(0,0); prio0
//  ph1: bar; read b(nf23); 16 MFMA Q(0,1)
//  ph2: bar; read aQ(mh1); 16 MFMA Q(1,1)
//  ph3: bar; (no reads; b nf01 kept in regs); 16 MFMA Q(1,0)
// Stage of j+1 always targets the buffer whose tile (j-1) was fully read
// >=1 barrier earlier -> provably race-free. vmcnt(0) at ph0 has 3-4 phases
// of issue-to-wait cover -> effectively free.
// ---------------------------------------------------------------------------
__global__ __launch_bounds__(512, 2) void loss_kernel(
        const _Float16* __restrict__ h,
        const int*   __restrict__ seg,
        const float* __restrict__ sq,
        double*      __restrict__ partials) {
    extern __shared__ _Float16 smem[];
    __shared__ double wred[8];

    int bid = blockIdx.x;
    int n   = bid & 7;                 // batch -> XCD round-robin
    int p   = bid >> 3;                // 0..63
    int tjj = p >> 3, tkk = p & 7;
    int j0  = tjj * BM, k0 = tkk * BN;

    int t    = threadIdx.x;
    int wid  = t >> 6;                 // 0..7
    int lane = t & 63;
    int wm   = wid >> 2;               // 0..1 : 128-row band
    int wn   = wid & 3;                // 0..3 : 64-col band
    int l15  = lane & 15;
    int lq   = lane >> 4;              // 0..3 : k-quarter

    const _Float16* baseH = h + (size_t)n * L * DDIM;

    // ---- staging geometry: inst = 8 rows x 128B; 32 insts per tile;
    // wave handles insts {4w..4w+3} of A and of B (8 gload_lds / thread / tile)
    int rl8 = lane >> 3;
    int lc  = (lane & 7) ^ rl8;
    const _Float16* srcA = baseH + (size_t)(j0 + rl8) * DDIM + lc * 8;
    const _Float16* srcB = baseH + (size_t)(k0 + rl8) * DDIM + lc * 8;

    #define STAGE(kt)                                                         \
    {                                                                         \
        _Float16* _A = smem + ((kt) & 1) * BUFSZ;                             \
        _Float16* _B = _A + TILE_SH;                                          \
        _Pragma("unroll")                                                     \
        for (int q = 0; q < 4; ++q) {                                         \
            int inst = wid * 4 + q;                                           \
            GLOAD_LDS16(srcA + (size_t)(inst * 8) * DDIM + (kt) * BK,         \
                        _A + inst * 512);                                     \
            GLOAD_LDS16(srcB + (size_t)(inst * 8) * DDIM + (kt) * BK,         \
                        _B + inst * 512);                                     \
        }                                                                     \
    }

    // ---- LDS read offsets (f16 units). R&7 == l15&7 for all frags.
    int x0 = ((0 + lq) ^ (l15 & 7)) << 3;        // ks=0 chunk
    int x1 = ((4 + lq) ^ (l15 & 7)) << 3;        // ks=1 chunk
    int arow[8], brow[4];
    #pragma unroll
    for (int mf = 0; mf < 8; ++mf) arow[mf] = (wm * 128 + mf * 16 + l15) * 64;
    #pragma unroll
    for (int nf = 0; nf < 4; ++nf) brow[nf] = (wn * 64 + nf * 16 + l15) * 64;

    f32x4 acc[8][4];
    #pragma unroll
    for (int mf = 0; mf < 8; ++mf)
        #pragma unroll
        for (int nf = 0; nf < 4; ++nf) acc[mf][nf] = (f32x4){0.f, 0.f, 0.f, 0.f};

    STAGE(0);   // prologue

    #pragma unroll 2
    for (int j = 0; j < NKT; ++j) {
        const _Float16* A = smem + (j & 1) * BUFSZ;
        const _Float16* B = A + TILE_SH;

        // ---------------- ph0: Q(0,0) ----------------
        asm volatile("s_waitcnt vmcnt(0)" ::: "memory");   // own tile-j writes
        __builtin_amdgcn_s_barrier();                      // all waves' writes
        f16x8 a[4][2], b01[2][2];
        #pragma unroll
        for (int mf = 0; mf < 4; ++mf) {
            a[mf][0] = *(const f16x8*)&A[arow[mf] + x0];
            a[mf][1] = *(const f16x8*)&A[arow[mf] + x1];
        }
        #pragma unroll
        for (int nf = 0; nf < 2; ++nf) {
            b01[nf][0] = *(const f16x8*)&B[brow[nf] + x0];
            b01[nf][1] = *(const f16x8*)&B[brow[nf] + x1];
        }
        if (j + 1 < NKT) STAGE(j + 1);                     // into other buffer
        asm volatile("s_waitcnt lgkmcnt(0)" ::: "memory");
        __builtin_amdgcn_sched_barrier(0);
        __builtin_amdgcn_s_setprio(1);
        #pragma unroll
        for (int mf = 0; mf < 4; ++mf)
            #pragma unroll
            for (int nf = 0; nf < 2; ++nf) {
                acc[mf][nf] = __builtin_amdgcn_mfma_f32_16x16x32_f16(
                    a[mf][0], b01[nf][0], acc[mf][nf], 0, 0, 0);
                acc[mf][nf] = __builtin_amdgcn_mfma_f32_16x16x32_f16(
                    a[mf][1], b01[nf][1], acc[mf][nf], 0, 0, 0);
            }
        __builtin_amdgcn_s_setprio(0);

        // ---------------- ph1: Q(0,1) ----------------
        __builtin_amdgcn_s_barrier();
        f16x8 b23[2][2];
        #pragma unroll
        for (int nf = 0; nf < 2; ++nf) {
            b23[nf][0] = *(const f16x8*)&B[brow[nf + 2] + x0];
            b23[nf][1] = *(const f16x8*)&B[brow[nf + 2] + x1];
        }
        asm volatile("s_waitcnt lgkmcnt(0)" ::: "memory");
        __builtin_amdgcn_sched_barrier(0);
        __builtin_amdgcn_s_setprio(1);
        #pragma unroll
        for (int mf = 0; mf < 4; ++mf)
            #pragma unroll
            for (int nf = 0; nf < 2; ++nf) {
                acc[mf][nf + 2] = __builtin_amdgcn_mfma_f32_16x16x32_f16(
                    a[mf][0], b23[nf][0], acc[mf][nf + 2], 0, 0, 0);
                acc[mf][nf + 2] = __builtin_amdgcn_mfma_f32_16x16x32_f16(
                    a[mf][1], b23[nf][1], acc[mf][nf + 2], 0, 0, 0);
            }
        __builtin_amdgcn_s_setprio(0);

        // ---------------- ph2: Q(1,1) ----------------
        __builtin_amdgcn_s_barrier();
        f16x8 a2[4][2];
        #pragma unroll
        for (int mf = 0; mf < 4; ++mf) {
            a2[mf][0] = *(const f16x8*)&A[arow[mf + 4] + x0];
            a2[mf][1] = *(const f16x8*)&A[arow[mf + 4] + x1];
        }
        asm volatile("s_waitcnt lgkmcnt(0)" ::: "memory");
        __builtin_amdgcn_sched_barrier(0);
        __builtin_amdgcn_s_setprio(1);
        #pragma unroll
        for (int mf = 0; mf < 4; ++mf)
            #pragma unroll
            for (int nf = 0; nf < 2; ++nf) {
                acc[mf + 4][nf + 2] = __builtin_amdgcn_mfma_f32_16x16x32_f16(
                    a2[mf][0], b23[nf][0], acc[mf + 4][nf + 2], 0, 0, 0);
                acc[mf + 4][nf + 2] = __builtin_amdgcn_mfma_f32_16x16x32_f16(
                    a2[mf][1], b23[nf][1], acc[mf + 4][nf + 2], 0, 0, 0);
            }
        __builtin_amdgcn_s_setprio(0);

        // ---------------- ph3: Q(1,0) (no reads) ----------------
        __builtin_amdgcn_s_barrier();
        __builtin_amdgcn_s_setprio(1);
        #pragma unroll
        for (int mf = 0; mf < 4; ++mf)
            #pragma unroll
            for (int nf = 0; nf < 2; ++nf) {
                acc[mf + 4][nf] = __builtin_amdgcn_mfma_f32_16x16x32_f16(
                    a2[mf][0], b01[nf][0], acc[mf + 4][nf], 0, 0, 0);
                acc[mf + 4][nf] = __builtin_amdgcn_mfma_f32_16x16x32_f16(
                    a2[mf][1], b01[nf][1], acc[mf + 4][nf], 0, 0, 0);
            }
        __builtin_amdgcn_s_setprio(0);
    }

    // ------------------- fused loss epilogue (full matrix, weight 1) -------
    // 16x16 C/D layout: col = lane&15, row = lq*4 + reg
    const int*   segb = seg + n * L;
    const float* sqb  = sq + n * L;

    float lsum = 0.0f;
    #pragma unroll
    for (int nf = 0; nf < 4; ++nf) {
        int k = k0 + wn * 64 + nf * 16 + l15;
        float sqk = sqb[k];
        int   sgk = segb[k];
        #pragma unroll
        for (int mf = 0; mf < 8; ++mf)
            #pragma unroll
            for (int reg = 0; reg < 4; ++reg) {
                int jj = j0 + wm * 128 + mf * 16 + lq * 4 + reg;
                float inner = acc[mf][nf][reg];
                float d2 = fmaxf(sqb[jj] + sqk - 2.0f * inner, 0.0f);
                float v;
                if (segb[jj] == sgk) {
                    v = ALPHA * d2;
                } else {
                    float dist = sqrtf(d2);
                    float hg = fmaxf(MARGIN - dist, 0.0f);
                    v = BETA * hg * hg;
                }
                lsum += v;
            }
    }

    double dsum = (double)lsum;
    #pragma unroll
    for (int off = 32; off > 0; off >>= 1)
        dsum += __shfl_down(dsum, off);
    if (lane == 0) wred[wid] = dsum;
    __syncthreads();
    if (t == 0) {
        double s = ((wred[0] + wred[1]) + (wred[2] + wred[3]))
                 + ((wred[4] + wred[5]) + (wred[6] + wred[7]));
        partials[bid] = s;
    }
}

// ---------------------------------------------------------------------------
// Kernel 3: deterministic final reduction -> mean.
// ---------------------------------------------------------------------------
__global__ __launch_bounds__(256) void reduce_kernel(const double* __restrict__ partials,
                                                     float* __restrict__ out,
                                                     int nPart, double invCount) {
    __shared__ double red[256];
    int t = threadIdx.x;
    double s = 0.0;
    for (int i = t; i < nPart; i += 256) s += partials[i];
    red[t] = s;
    __syncthreads();
    #pragma unroll
    for (int k = 128; k > 0; k >>= 1) {
        if (t < k) red[t] += red[t + k];
        __syncthreads();
    }
    if (t == 0) out[0] = (float)(red[0] * invCount);
}

extern "C" void kernel_launch(void* const* d_in, const int* in_sizes, int n_in,
                              void* d_out, int out_size, void* d_ws, size_t ws_size,
                              hipStream_t stream) {
    const float* pred = (const float*)d_in[0];
    const int*   seg  = (const int*)d_in[1];
    float* out = (float*)d_out;

    const size_t HALF = (size_t)NBATCH * L * DDIM;
    _Float16* h        = (_Float16*)d_ws;                    // 16.78 MB
    float*    sq       = (float*)(h + HALF);                 // 64 KB
    double*   partials = (double*)(sq + NBATCH * L);         // 4 KB

    // allow 128KB dynamic LDS (idempotent; safe under graph capture per R10)
    (void)hipFuncSetAttribute((const void*)loss_kernel,
                              hipFuncAttributeMaxDynamicSharedMemorySize,
                              LDS_BYTES);

    conv_kernel<<<NBATCH * L / 4, 256, 0, stream>>>(pred, h, sq);
    loss_kernel<<<TOTAL_BLOCKS, 512, LDS_BYTES, stream>>>(h, seg, sq, partials);
    reduce_kernel<<<1, 256, 0, stream>>>(partials, out, TOTAL_BLOCKS,
                                         1.0 / (double)((size_t)NBATCH * L * L));
}

// Round 14
// 74.319 us; speedup vs baseline: 1.0256x; 1.0256x over previous
//
#include <hip/hip_runtime.h>
#include <math.h>

#define L      2048
#define DDIM   512
#define NBATCH 8
#define BM     256
#define BN     128
#define NKS    (DDIM / 16)               // 32 k-steps of 16
#define NKTI   (L / BN)                  // 16
#define PAIRS  72                        // sum_{tj=0..7} (16 - 2*tj)
#define TOTAL_BLOCKS (NBATCH * PAIRS)    // 576

#define PANSZ  16384     // f16 per packed panel (32 rows x 512 k)
#define KSSZ   512       // f16 per (panel, kstep) fragment block (1 KB)

#define ALPHA  0.1f
#define BETA   0.3f
#define MARGIN 2.0f

typedef _Float16 f16x8 __attribute__((ext_vector_type(8)));
typedef __attribute__((ext_vector_type(16))) float f32x16;

// ---------------------------------------------------------------------------
// Kernel 1: fp32 -> fp16 PACKED in MFMA-fragment order + per-row sq norms.
// Packed layout: pk[panel][kstep][frag-lane][8], panel = row>>5 (global),
// frag-lane = (row&31) + 32*khalf, so a wave's 32x32x16 A/B fragment is ONE
// contiguous 1KB block: lane l -> row panel*32+(l&31), k = kstep*16+(l>>5)*8+e
// (fragment mapping verified correct in R11: absmax == 0).
// ---------------------------------------------------------------------------
__global__ __launch_bounds__(256) void conv_kernel(const float* __restrict__ pred,
                                                   _Float16* __restrict__ pk,
                                                   float* __restrict__ sq) {
    int w    = threadIdx.x >> 6;
    int lane = threadIdx.x & 63;
    int row  = blockIdx.x * 4 + w;               // global row 0..16383
    const float* p = pred + (size_t)row * DDIM + lane * 8;
    float4 v0 = *(const float4*)(p);
    float4 v1 = *(const float4*)(p + 4);
    float vals[8] = {v0.x, v0.y, v0.z, v0.w, v1.x, v1.y, v1.z, v1.w};
    f16x8 hv;
    float s = 0.0f;
    #pragma unroll
    for (int i = 0; i < 8; ++i) {
        float x = vals[i];
        s = fmaf(x, x, s);
        hv[i] = (_Float16)x;
    }
    // this thread's 8 k's: k0 = lane*8 -> kstep = lane>>1, khalf = lane&1
    int kstep = lane >> 1;
    int khalf = lane & 1;
    int lrow  = row & 31;
    size_t off = (size_t)(row >> 5) * PANSZ + kstep * KSSZ + (lrow + 32 * khalf) * 8;
    *(f16x8*)(pk + off) = hv;
    #pragma unroll
    for (int o = 32; o > 0; o >>= 1) s += __shfl_down(s, o);
    if (lane == 0) sq[row] = s;
}

// ---------------------------------------------------------------------------
// Kernel 2: register-direct fp16 Gram GEMM on packed fragments + fused loss.
// NO LDS, NO barriers, NO waitcnt choreography. 256x128 block tile, 8 waves
// (4M x 2N, per-wave 64x64 = 2x2 frags of 32x32), mfma_f32_32x32x16_f16.
// Per k-step: 4 coalesced 1KB fragment loads (depth-1 register prefetch)
// + 4 MFMA (32 cyc each). Data L2-resident per XCD (2.1 MB/batch).
// Symmetric grid: pairs (tj, tk>=2tj), per-element weights {2,1,0}.
// ---------------------------------------------------------------------------
__global__ __launch_bounds__(512, 4) void loss_kernel(
        const _Float16* __restrict__ pk,
        const int*   __restrict__ seg,
        const float* __restrict__ sq,
        double*      __restrict__ partials) {
    __shared__ double wred[8];

    int bid = blockIdx.x;
    int n = bid & 7;            // batch -> XCD round-robin (L2 locality)
    int p = bid >> 3;           // 0..71
    int tj = 0;                 // widths 16,14,...,2
    while (p >= NKTI - 2 * tj) { p -= NKTI - 2 * tj; ++tj; }
    int tk = 2 * tj + p;
    int j0 = tj * BM, k0 = tk * BN;

    int t    = threadIdx.x;
    int wid  = t >> 6;          // 0..7
    int lane = t & 63;
    int wm   = wid >> 1;        // 0..3 : 64-row band of 256
    int wn   = wid & 1;         // 0..1 : 64-col band of 128
    int l31  = lane & 31;
    int hsel = lane >> 5;

    const _Float16* base = pk + (size_t)n * L * DDIM;

    // fragment block pointers (panel index; kstep advances by KSSZ)
    int pA = (j0 + wm * 64) >> 5;        // tj*8 + wm*2
    int pB = (k0 + wn * 64) >> 5;        // tk*4 + wn*2
    const _Float16* pa[2];
    const _Float16* pb[2];
    #pragma unroll
    for (int mf = 0; mf < 2; ++mf)
        pa[mf] = base + (size_t)(pA + mf) * PANSZ + lane * 8;
    #pragma unroll
    for (int nf = 0; nf < 2; ++nf)
        pb[nf] = base + (size_t)(pB + nf) * PANSZ + lane * 8;

    f32x16 acc[2][2];
    #pragma unroll
    for (int mf = 0; mf < 2; ++mf)
        #pragma unroll
        for (int nf = 0; nf < 2; ++nf)
            #pragma unroll
            for (int r = 0; r < 16; ++r) acc[mf][nf][r] = 0.0f;

    f16x8 a0 = *(const f16x8*)(pa[0]);
    f16x8 a1 = *(const f16x8*)(pa[1]);
    f16x8 b0 = *(const f16x8*)(pb[0]);
    f16x8 b1 = *(const f16x8*)(pb[1]);

    #pragma unroll
    for (int ks = 0; ks < NKS; ++ks) {
        f16x8 na0, na1, nb0, nb1;
        if (ks + 1 < NKS) {
            int o = (ks + 1) * KSSZ;
            na0 = *(const f16x8*)(pa[0] + o);
            na1 = *(const f16x8*)(pa[1] + o);
            nb0 = *(const f16x8*)(pb[0] + o);
            nb1 = *(const f16x8*)(pb[1] + o);
        }
        acc[0][0] = __builtin_amdgcn_mfma_f32_32x32x16_f16(a0, b0, acc[0][0], 0, 0, 0);
        acc[0][1] = __builtin_amdgcn_mfma_f32_32x32x16_f16(a0, b1, acc[0][1], 0, 0, 0);
        acc[1][0] = __builtin_amdgcn_mfma_f32_32x32x16_f16(a1, b0, acc[1][0], 0, 0, 0);
        acc[1][1] = __builtin_amdgcn_mfma_f32_32x32x16_f16(a1, b1, acc[1][1], 0, 0, 0);
        if (ks + 1 < NKS) {
            a0 = na0; a1 = na1; b0 = nb0; b1 = nb1;
        }
    }

    // ------------------- fused loss epilogue -------------------
    // 32x32 C/D layout: col = lane&31, row = (reg&3) + 8*(reg>>2) + 4*(lane>>5)
    const int*   segb = seg + n * L;
    const float* sqb  = sq + n * L;

    float lsum = 0.0f;    // weighted: skip j>k, 2x for j<k, 1x for j==k
    #pragma unroll
    for (int nf = 0; nf < 2; ++nf) {
        int k = k0 + wn * 64 + nf * 32 + l31;
        float sqk = sqb[k];
        int   sgk = segb[k];
        #pragma unroll
        for (int mf = 0; mf < 2; ++mf)
            #pragma unroll
            for (int r = 0; r < 16; ++r) {
                int j = j0 + wm * 64 + mf * 32 + (r & 3) + 8 * (r >> 2) + 4 * hsel;
                if (j > k) continue;
                float inner = acc[mf][nf][r];
                float d2 = fmaxf(sqb[j] + sqk - 2.0f * inner, 0.0f);
                float v;
                if (segb[j] == sgk) {
                    v = ALPHA * d2;
                } else {
                    float dist = sqrtf(d2);
                    float hg = fmaxf(MARGIN - dist, 0.0f);
                    v = BETA * hg * hg;
                }
                lsum += (j < k) ? 2.0f * v : v;
            }
    }

    double dsum = (double)lsum;
    #pragma unroll
    for (int off = 32; off > 0; off >>= 1)
        dsum += __shfl_down(dsum, off);
    if (lane == 0) wred[wid] = dsum;
    __syncthreads();
    if (t == 0) {
        double s = ((wred[0] + wred[1]) + (wred[2] + wred[3]))
                 + ((wred[4] + wred[5]) + (wred[6] + wred[7]));
        partials[bid] = s;
    }
}

// ---------------------------------------------------------------------------
// Kernel 3: deterministic final reduction -> mean.
// ---------------------------------------------------------------------------
__global__ __launch_bounds__(256) void reduce_kernel(const double* __restrict__ partials,
                                                     float* __restrict__ out,
                                                     int nPart, double invCount) {
    __shared__ double red[256];
    int t = threadIdx.x;
    double s = 0.0;
    for (int i = t; i < nPart; i += 256) s += partials[i];
    red[t] = s;
    __syncthreads();
    #pragma unroll
    for (int k = 128; k > 0; k >>= 1) {
        if (t < k) red[t] += red[t + k];
        __syncthreads();
    }
    if (t == 0) out[0] = (float)(red[0] * invCount);
}

extern "C" void kernel_launch(void* const* d_in, const int* in_sizes, int n_in,
                              void* d_out, int out_size, void* d_ws, size_t ws_size,
                              hipStream_t stream) {
    const float* pred = (const float*)d_in[0];
    const int*   seg  = (const int*)d_in[1];
    float* out = (float*)d_out;

    const size_t HALF = (size_t)NBATCH * L * DDIM;
    _Float16* pk       = (_Float16*)d_ws;                    // 16.78 MB packed
    float*    sq       = (float*)(pk + HALF);                // 64 KB
    double*   partials = (double*)(sq + NBATCH * L);         // 4.6 KB

    conv_kernel<<<NBATCH * L / 4, 256, 0, stream>>>(pred, pk, sq);
    loss_kernel<<<TOTAL_BLOCKS, 512, 0, stream>>>(pk, seg, sq, partials);
    reduce_kernel<<<1, 256, 0, stream>>>(partials, out, TOTAL_BLOCKS,
                                         1.0 / (double)((size_t)NBATCH * L * L));
}

// Round 15
// 65.800 us; speedup vs baseline: 1.1584x; 1.1295x over previous
//
#include <hip/hip_runtime.h>
#include <math.h>

#define L      2048
#define DDIM   512
#define NBATCH 8
#define BM     128
#define BN     128
#define BK     64
#define NKT    (DDIM / BK)               // 8 K-tiles
#define NTILE  (L / BM)                  // 16
#define NPAIR  (NTILE * (NTILE + 1) / 2) // 136
#define TOTAL_BLOCKS (NBATCH * NPAIR)    // 1088

#define ALPHA  0.1f
#define BETA   0.3f
#define MARGIN 2.0f

typedef _Float16 f16x8 __attribute__((ext_vector_type(8)));
typedef __attribute__((ext_vector_type(16))) float f32x16;

// Buffer (32 KB): A[128 rows x 128B] then B[128 rows x 128B]; x2 buffers.
// Row = 8 chunks of 16B; physical chunk = logical ^ (row & 7) (R8-proven
// conflict-free). All ds_read addresses = 1 persistent VGPR + 16-bit imm.
#define TILE_SH 8192       // f16 per tile (16 KB)
#define BUFSZ   16384      // f16 per buffer (32 KB)

#define GLOAD_LDS16(g, l) __builtin_amdgcn_global_load_lds(              \
    (const __attribute__((address_space(1))) unsigned int*)(g),          \
    (__attribute__((address_space(3))) unsigned int*)(l), 16, 0, 0)

// ---------------------------------------------------------------------------
// Kernel 1: fp32 -> fp16 + per-row squared norms (exact fp32).
// ---------------------------------------------------------------------------
__global__ __launch_bounds__(256) void conv_kernel(const float* __restrict__ pred,
                                                   _Float16* __restrict__ h,
                                                   float* __restrict__ sq) {
    int w    = threadIdx.x >> 6;
    int lane = threadIdx.x & 63;
    int row  = blockIdx.x * 4 + w;
    const float* p = pred + (size_t)row * DDIM + lane * 8;
    float4 v0 = *(const float4*)(p);
    float4 v1 = *(const float4*)(p + 4);
    float vals[8] = {v0.x, v0.y, v0.z, v0.w, v1.x, v1.y, v1.z, v1.w};
    f16x8 hv;
    float s = 0.0f;
    #pragma unroll
    for (int i = 0; i < 8; ++i) {
        float x = vals[i];
        s = fmaf(x, x, s);
        hv[i] = (_Float16)x;
    }
    *(f16x8*)(h + (size_t)row * DDIM + lane * 8) = hv;
    #pragma unroll
    for (int off = 32; off > 0; off >>= 1) s += __shfl_down(s, off);
    if (lane == 0) sq[row] = s;
}

// ---------------------------------------------------------------------------
// Kernel 2: fp16 Gram GEMM + fused loss. R8 skeleton, zero-VALU K-loop:
// - full unroll (8 tiles): buffer select + all sub-offsets compile-time
// - 8 precomputed per-lane LDS indices -> ds_read_b128 vaddr + 16-bit imm
// - 2 persistent global pointers -> global_load_lds + 13-bit imm (kt*128B)
// Per tile: STAGE(kt+1) first (max cover), 16 ds_read, 16 MFMA (setprio),
// vmcnt(0), ONE s_barrier. 2 blocks/CU.
// ---------------------------------------------------------------------------
__global__ __launch_bounds__(256) void loss_kernel(
        const _Float16* __restrict__ h,
        const int*   __restrict__ seg,
        const float* __restrict__ sq,
        double*      __restrict__ partials) {
    __shared__ _Float16 smem[2 * BUFSZ];   // 64 KB
    __shared__ double wred[4];

    int bid = blockIdx.x;
    int n = bid & 7;            // batch -> XCD round-robin (L2 locality)
    int p = bid >> 3;           // 0..135
    int tj = 0;
    while (true) {
        int rl2 = NTILE - tj;
        if (p < rl2) break;
        p -= rl2;
        ++tj;
    }
    int tk = tj + p;
    int j0 = tj * BM, k0 = tk * BN;

    int t    = threadIdx.x;
    int w    = t >> 6;          // 0..3
    int lane = t & 63;
    int wr   = w >> 1, wc = w & 1;     // 64x64 quadrant
    int l31  = lane & 31;
    int hsel = lane >> 5;              // 0/1: k-halfslice of the frag

    const _Float16* baseH = h + (size_t)n * L * DDIM;

    // ---- staging: wave w covers rows w*32..w*32+31 of A and of B
    // (4 insts each, 8 rows/inst). lane -> row rl8 = lane>>3, logical chunk
    // lc = (lane&7) ^ rl8 (source pre-swizzle; row&7 == rl8).
    int rl8 = lane >> 3;
    int lc  = (lane & 7) ^ rl8;
    const _Float16* srcA = baseH + (size_t)(j0 + w * 32 + rl8) * DDIM + lc * 8;
    const _Float16* srcB = baseH + (size_t)(k0 + w * 32 + rl8) * DDIM + lc * 8;
    _Float16* dstA = smem + w * 2048;            // A inst base (f16 units)
    _Float16* dstB = smem + TILE_SH + w * 2048;  // B inst base

    #define STAGE(kt, cur)                                                    \
    {                                                                         \
        _Pragma("unroll")                                                     \
        for (int q = 0; q < 4; ++q) {                                         \
            GLOAD_LDS16(srcA + (size_t)(q * 8) * DDIM + (kt) * BK,            \
                        dstA + (cur) * BUFSZ + q * 512);                      \
            GLOAD_LDS16(srcB + (size_t)(q * 8) * DDIM + (kt) * BK,            \
                        dstB + (cur) * BUFSZ + q * 512);                      \
        }                                                                     \
    }

    // ---- persistent per-lane LDS read indices (f16 units), loop-invariant.
    // frag addr: row R = band*64 + frag*32 + l31; byte row stride 128;
    // chunk = (ks*2 + hsel) ^ (l31 & 7). frag adds 2048 f16, buf adds 16384.
    int s7 = l31 & 7;
    int ra = (wr * 64 + l31) * 64;
    int rb = (wc * 64 + l31) * 64 + TILE_SH;
    int iA0 = ra + (((0 + hsel) ^ s7) << 3);
    int iA1 = ra + (((2 + hsel) ^ s7) << 3);
    int iA2 = ra + (((4 + hsel) ^ s7) << 3);
    int iA3 = ra + (((6 + hsel) ^ s7) << 3);
    int iB0 = rb + (((0 + hsel) ^ s7) << 3);
    int iB1 = rb + (((2 + hsel) ^ s7) << 3);
    int iB2 = rb + (((4 + hsel) ^ s7) << 3);
    int iB3 = rb + (((6 + hsel) ^ s7) << 3);

    f32x16 acc[2][2];
    #pragma unroll
    for (int m = 0; m < 2; ++m)
        #pragma unroll
        for (int nn = 0; nn < 2; ++nn)
            #pragma unroll
            for (int r = 0; r < 16; ++r) acc[m][nn][r] = 0.0f;

    STAGE(0, 0);
    asm volatile("s_waitcnt vmcnt(0)" ::: "memory");
    __builtin_amdgcn_s_barrier();

    #pragma unroll
    for (int kt = 0; kt < NKT; ++kt) {
        const int cur = kt & 1;                  // compile-time under unroll
        if (kt + 1 < NKT) STAGE(kt + 1, cur ^ 1);

        #pragma unroll
        for (int ks = 0; ks < 4; ++ks) {
            int iA = (ks == 0) ? iA0 : (ks == 1) ? iA1 : (ks == 2) ? iA2 : iA3;
            int iB = (ks == 0) ? iB0 : (ks == 1) ? iB1 : (ks == 2) ? iB2 : iB3;
            f16x8 a0 = *(const f16x8*)&smem[iA + cur * BUFSZ];
            f16x8 a1 = *(const f16x8*)&smem[iA + cur * BUFSZ + 2048];
            f16x8 b0 = *(const f16x8*)&smem[iB + cur * BUFSZ];
            f16x8 b1 = *(const f16x8*)&smem[iB + cur * BUFSZ + 2048];
            __builtin_amdgcn_s_setprio(1);
            acc[0][0] = __builtin_amdgcn_mfma_f32_32x32x16_f16(a0, b0, acc[0][0], 0, 0, 0);
            acc[0][1] = __builtin_amdgcn_mfma_f32_32x32x16_f16(a0, b1, acc[0][1], 0, 0, 0);
            acc[1][0] = __builtin_amdgcn_mfma_f32_32x32x16_f16(a1, b0, acc[1][0], 0, 0, 0);
            acc[1][1] = __builtin_amdgcn_mfma_f32_32x32x16_f16(a1, b1, acc[1][1], 0, 0, 0);
            __builtin_amdgcn_s_setprio(0);
        }

        // own STAGE(kt+1) drained (covered by 16 ds_read + 16 MFMA), then
        // block-wide visibility + WAR release. ONE barrier per K-tile.
        asm volatile("s_waitcnt vmcnt(0)" ::: "memory");
        __builtin_amdgcn_s_barrier();
    }

    // ------------------- fused loss epilogue -------------------
    // 32x32 C/D layout: col = lane&31, row = (reg&3) + 8*(reg>>2) + 4*(lane>>5)
    const int*   segb = seg + n * L;
    const float* sqb  = sq + n * L;

    float lsum = 0.0f;
    #pragma unroll
    for (int nn = 0; nn < 2; ++nn) {
        int k = k0 + wc * 64 + nn * 32 + l31;
        float sqk = sqb[k];
        int   sgk = segb[k];
        #pragma unroll
        for (int m = 0; m < 2; ++m)
            #pragma unroll
            for (int r = 0; r < 16; ++r) {
                int j = j0 + wr * 64 + m * 32 + (r & 3) + 8 * (r >> 2) + 4 * hsel;
                float inner = acc[m][nn][r];
                float d2 = fmaxf(sqb[j] + sqk - 2.0f * inner, 0.0f);
                float v;
                if (segb[j] == sgk) {
                    v = ALPHA * d2;
                } else {
                    float dist = sqrtf(d2);
                    float hg = fmaxf(MARGIN - dist, 0.0f);
                    v = BETA * hg * hg;
                }
                lsum += v;
            }
    }

    // per-wave shuffle reduction (no LDS tree -> no bank conflicts)
    double wgt = (tj == tk) ? 1.0 : 2.0;
    double dsum = (double)lsum * wgt;
    #pragma unroll
    for (int off = 32; off > 0; off >>= 1)
        dsum += __shfl_down(dsum, off);
    if (lane == 0) wred[w] = dsum;
    __syncthreads();
    if (t == 0) partials[bid] = (wred[0] + wred[1]) + (wred[2] + wred[3]);
}

// ---------------------------------------------------------------------------
// Kernel 3: deterministic final reduction -> mean.
// ---------------------------------------------------------------------------
__global__ __launch_bounds__(256) void reduce_kernel(const double* __restrict__ partials,
                                                     float* __restrict__ out,
                                                     int nPart, double invCount) {
    __shared__ double red[256];
    int t = threadIdx.x;
    double s = 0.0;
    for (int i = t; i < nPart; i += 256) s += partials[i];
    red[t] = s;
    __syncthreads();
    #pragma unroll
    for (int k = 128; k > 0; k >>= 1) {
        if (t < k) red[t] += red[t + k];
        __syncthreads();
    }
    if (t == 0) out[0] = (float)(red[0] * invCount);
}

extern "C" void kernel_launch(void* const* d_in, const int* in_sizes, int n_in,
                              void* d_out, int out_size, void* d_ws, size_t ws_size,
                              hipStream_t stream) {
    const float* pred = (const float*)d_in[0];
    const int*   seg  = (const int*)d_in[1];
    float* out = (float*)d_out;

    const size_t HALF = (size_t)NBATCH * L * DDIM;
    _Float16* h        = (_Float16*)d_ws;                    // 16.78 MB
    float*    sq       = (float*)(h + HALF);                 // 64 KB
    double*   partials = (double*)(sq + NBATCH * L);         // 8.7 KB

    conv_kernel<<<NBATCH * L / 4, 256, 0, stream>>>(pred, h, sq);
    loss_kernel<<<TOTAL_BLOCKS, 256, 0, stream>>>(h, seg, sq, partials);
    reduce_kernel<<<1, 256, 0, stream>>>(partials, out, TOTAL_BLOCKS,
                                         1.0 / (double)((size_t)NBATCH * L * L));
}